// Round 1
// baseline (203.399 us; speedup 1.0000x reference)
//
#include <hip/hip_runtime.h>
#include <math.h>

#define N_F   128
#define N_D   2048
#define BATCH 8
#define ALPHA 0.2f

// ws layout (floats):
//   [0   .. 127]  sq_orig[i]   = ||positions_orig[i]||^2
//   [128 .. 255]  sq_final[i]  = ||pos_final[i]||^2   (atomic-accumulated)
//   [256]         best_idx (stored as int)
//   [257]         better flag (1.0 / 0.0)
//   [512 .. 512+128*2048-1]  pos_final rows
#define WS_SQO   0
#define WS_SQF   128
#define WS_BEST  256
#define WS_BET   257
#define WS_POSF  512

// K1: per-firefly squared norm of original positions; zero-init sq_final.
__global__ void ff_k1_norms(const float* __restrict__ pos, float* __restrict__ ws) {
    const int i   = blockIdx.x;
    const int tid = threadIdx.x;            // 256 threads
    const float* row = pos + (size_t)i * N_D;
    // each thread: 2 float4s (2048 / (256*4) = 2)
    float4 a = *(const float4*)(row + tid * 4);
    float4 b = *(const float4*)(row + 1024 + tid * 4);
    float ss = a.x*a.x + a.y*a.y + a.z*a.z + a.w*a.w
             + b.x*b.x + b.y*b.y + b.z*b.z + b.w*b.w;
    __shared__ float red[256];
    red[tid] = ss;
    __syncthreads();
    for (int s = 128; s > 0; s >>= 1) {
        if (tid < s) red[tid] += red[tid + s];
        __syncthreads();
    }
    if (tid == 0) {
        ws[WS_SQO + i] = red[0];
        ws[WS_SQF + i] = 0.0f;   // zero-init for K2 atomics
    }
}

// K2: pos_final[i] = positions[i] + ALPHA * sum_{accepted j} noise[i,j,:]
// grid (128 fireflies, 2 dim-chunks of 1024), 256 threads, float4/thread.
__global__ void ff_k2_move(const float* __restrict__ pos,
                           const float* __restrict__ noise,
                           float* __restrict__ ws) {
    const int i   = blockIdx.x;
    const int c   = blockIdx.y;
    const int tid = threadIdx.x;
    __shared__ float s_sq[N_F];
    __shared__ unsigned char s_list[N_F];
    __shared__ int s_n;
    __shared__ float s_red[256];

    if (tid < N_F) s_sq[tid] = ws[WS_SQO + tid];
    __syncthreads();
    const float si = s_sq[i];
    if (tid == 0) {
        int n = 0;
        for (int j = 0; j < N_F; ++j)
            if (j != i && s_sq[j] < si) s_list[n++] = (unsigned char)j;
        s_n = n;
    }
    __syncthreads();
    const int nacc = s_n;

    const int d0 = c * 1024 + tid * 4;
    const float* nbase = noise + (size_t)i * N_F * N_D + d0;

    float4 acc = make_float4(0.f, 0.f, 0.f, 0.f);
    #pragma unroll 8
    for (int t = 0; t < nacc; ++t) {
        const float4 v = *(const float4*)(nbase + (size_t)s_list[t] * N_D);
        acc.x += v.x; acc.y += v.y; acc.z += v.z; acc.w += v.w;
    }

    const float4 p = *(const float4*)(pos + (size_t)i * N_D + d0);
    float4 pf;
    pf.x = p.x + ALPHA * acc.x;
    pf.y = p.y + ALPHA * acc.y;
    pf.z = p.z + ALPHA * acc.z;
    pf.w = p.w + ALPHA * acc.w;
    *(float4*)(ws + WS_POSF + (size_t)i * N_D + d0) = pf;

    float ss = pf.x*pf.x + pf.y*pf.y + pf.z*pf.z + pf.w*pf.w;
    s_red[tid] = ss;
    __syncthreads();
    for (int s = 128; s > 0; s >>= 1) {
        if (tid < s) s_red[tid] += s_red[tid + s];
        __syncthreads();
    }
    if (tid == 0) atomicAdd(&ws[WS_SQF + i], s_red[0]);
}

// K3: argmin over sq_final (first-index tie-break), better = norm < best_intensity.
__global__ void ff_k3_argmin(const float* __restrict__ best_intensity,
                             float* __restrict__ ws) {
    const int tid = threadIdx.x;            // 128 threads
    __shared__ float sv[N_F];
    __shared__ int   sidx[N_F];
    sv[tid]   = ws[WS_SQF + tid];
    sidx[tid] = tid;
    __syncthreads();
    for (int s = 64; s > 0; s >>= 1) {
        if (tid < s) {
            float v2 = sv[tid + s];
            int   i2 = sidx[tid + s];
            if (v2 < sv[tid] || (v2 == sv[tid] && i2 < sidx[tid])) {
                sv[tid] = v2; sidx[tid] = i2;
            }
        }
        __syncthreads();
    }
    if (tid == 0) {
        ((int*)ws)[WS_BEST] = sidx[0];
        ws[WS_BET] = (sqrtf(sv[0]) < best_intensity[0]) ? 1.0f : 0.0f;
    }
}

// K4: broadcast winning row (or best_position) to (BATCH, N_D).
__global__ void ff_k4_bcast(const float* __restrict__ best_position,
                            const float* __restrict__ ws,
                            float* __restrict__ out) {
    const int idx = blockIdx.x * blockDim.x + threadIdx.x;   // 0..4095 (float4 units)
    const int d   = (idx << 2) & (N_D - 1);
    const int best = ((const int*)ws)[WS_BEST];
    const bool better = ws[WS_BET] > 0.5f;
    float4 v;
    if (better) v = *(const float4*)(ws + WS_POSF + (size_t)best * N_D + d);
    else        v = *(const float4*)(best_position + d);
    *(float4*)(out + (size_t)idx * 4) = v;
}

extern "C" void kernel_launch(void* const* d_in, const int* in_sizes, int n_in,
                              void* d_out, int out_size, void* d_ws, size_t ws_size,
                              hipStream_t stream) {
    const float* positions      = (const float*)d_in[1];
    const float* noise          = (const float*)d_in[2];
    const float* best_position  = (const float*)d_in[3];
    const float* best_intensity = (const float*)d_in[4];
    float* ws  = (float*)d_ws;
    float* out = (float*)d_out;

    ff_k1_norms<<<N_F, 256, 0, stream>>>(positions, ws);
    dim3 g2(N_F, 2);
    ff_k2_move<<<g2, 256, 0, stream>>>(positions, noise, ws);
    ff_k3_argmin<<<1, N_F, 0, stream>>>(best_intensity, ws);
    ff_k4_bcast<<<(BATCH * N_D) / (256 * 4), 256, 0, stream>>>(best_position, ws, out);
}